// Round 11
// baseline (41.648 us; speedup 1.0000x reference)
//
#include <hip/hip_runtime.h>

#define NROWS 4096
#define DDIM  256
#define BDIM  16
#define RBLKS 256           // row-blocks, 16 rows each (authoritative kernel1)
#define BSETS 4
#define NB1   (RBLKS * BSETS)
#define WS2_OFF 4096        // float offset of probe scratch (bytes 16384..20480)

// ---------- PROBE (A/B measurement): thread-per-quarter-row ----------
// Block i: instance b = ((i&15)+(i>>4)+(i>>8))&15, row-chunk = i>>4 (64 rows).
// (bijective; CU-resident blocks {c+256k} get 4 distinct b at stratified chunks)
// Thread t: row r = t>>2 within chunk, quarter q = t&3. Each thread streams a
// CONTIGUOUS 256 B span of each tensor (16 independent float4 loads), computes
// dot/ns/nc per-thread, 2-stage shuffle to merge quarters, per-thread cos.
// Only 8 shuffle ops per 4 rows (vs 18 per row in early versions); max ILP.
// Writes partials to ws2 — nothing reads them; correctness is carried by the
// authoritative pipeline below. Bench delta vs 20.6us = this kernel's time.
__global__ __launch_bounds__(256) void cos_probe_kernel(
    const float* __restrict__ stat, const float* __restrict__ con,
    const int* __restrict__ lens, float* __restrict__ ws2) {
  const int i     = blockIdx.x;
  const int chunk = i >> 4;                                // 0..63
  const int b     = ((i & 15) + (i >> 4) + (i >> 8)) & 15; // 0..15
  const int t     = threadIdx.x;
  const int r     = t >> 2;
  const int q     = t & 3;
  const int n     = chunk * 64 + r;
  const int len   = lens[b];
  const bool valid = (n < len);

  float dot = 0.f, ns = 0.f, nc = 0.f;
  if (valid) {
    const size_t base = ((size_t)b * NROWS + (size_t)n) * DDIM + (size_t)(q << 6);
    const float* pa = stat + base;
    const float* pc = con + base;
    #pragma unroll
    for (int m = 0; m < 16; ++m) {
      const float4 a = *reinterpret_cast<const float4*>(pa + (m << 2));
      const float4 c = *reinterpret_cast<const float4*>(pc + (m << 2));
      dot = fmaf(a.x, c.x, fmaf(a.y, c.y, fmaf(a.z, c.z, fmaf(a.w, c.w, dot))));
      ns  = fmaf(a.x, a.x, fmaf(a.y, a.y, fmaf(a.z, a.z, fmaf(a.w, a.w, ns))));
      nc  = fmaf(c.x, c.x, fmaf(c.y, c.y, fmaf(c.z, c.z, fmaf(c.w, c.w, nc))));
    }
  }
  // merge the row's 4 quarters (lanes r*4+{0..3} are in the same wave)
  dot += __shfl_xor(dot, 1); ns += __shfl_xor(ns, 1); nc += __shfl_xor(nc, 1);
  dot += __shfl_xor(dot, 2); ns += __shfl_xor(ns, 2); nc += __shfl_xor(nc, 2);
  float cosv = valid ? dot * rsqrtf(ns) * rsqrtf(nc) : 0.0f;
  // wave-sum (each row counted 4x -> scale 0.25)
  #pragma unroll
  for (int off = 4; off < 64; off <<= 1) cosv += __shfl_xor(cosv, off);

  __shared__ float sh[4];
  if ((t & 63) == 0) sh[t >> 6] = cosv * 0.25f;
  __syncthreads();
  if (t == 0) ws2[b * 64 + chunk] = sh[0] + sh[1] + sh[2] + sh[3];
}

// ---------- AUTHORITATIVE kernel1 (R6 verbatim, 20.6us total) ----------
__global__ __launch_bounds__(256) void cos_partial_kernel(
    const float* __restrict__ stat, const float* __restrict__ con,
    const int* __restrict__ lens, float* __restrict__ ws) {
  const int rblk = blockIdx.x >> 2;
  const int bset = blockIdx.x & (BSETS - 1);
  const int wave = threadIdx.x >> 6;
  const int lane = threadIdx.x & 63;
  const int g    = lane >> 4;
  const int j    = lane & 15;

  const int n  = rblk * 16 + wave * 4 + g;
  const int b0 = bset * 4;

  float acc[4];
  #pragma unroll
  for (int bi = 0; bi < 4; ++bi) {
    const int b      = b0 + bi;
    const int len    = lens[b];
    const bool valid = (n < len);

    float dot = 0.0f, ns = 0.0f, nc = 0.0f;
    if (valid) {
      const size_t base = (size_t)b * (NROWS * DDIM) + (size_t)n * DDIM + (j << 2);
      const float* pa = stat + base;
      const float* pc = con + base;
      #pragma unroll
      for (int m = 0; m < 4; ++m) {
        const float4 a = *reinterpret_cast<const float4*>(pa + (m << 6));
        const float4 c = *reinterpret_cast<const float4*>(pc + (m << 6));
        dot = fmaf(a.x, c.x, fmaf(a.y, c.y, fmaf(a.z, c.z, fmaf(a.w, c.w, dot))));
        ns  = fmaf(a.x, a.x, fmaf(a.y, a.y, fmaf(a.z, a.z, fmaf(a.w, a.w, ns))));
        nc  = fmaf(c.x, c.x, fmaf(c.y, c.y, fmaf(c.z, c.z, fmaf(c.w, c.w, nc))));
      }
    }
    #pragma unroll
    for (int off = 1; off < 16; off <<= 1) {
      dot += __shfl_xor(dot, off);
      ns  += __shfl_xor(ns,  off);
      nc  += __shfl_xor(nc,  off);
    }
    float cosv = valid ? dot * rsqrtf(ns) * rsqrtf(nc) : 0.0f;
    cosv += __shfl_xor(cosv, 16);
    cosv += __shfl_xor(cosv, 32);
    acc[bi] = cosv;
  }

  __shared__ float sh[4][4];
  if (lane == 0) {
    #pragma unroll
    for (int bi = 0; bi < 4; ++bi) sh[wave][bi] = acc[bi];
  }
  __syncthreads();
  if (threadIdx.x < 4) {
    const int b = b0 + threadIdx.x;
    ws[b * RBLKS + rblk] =
        sh[0][threadIdx.x] + sh[1][threadIdx.x] + sh[2][threadIdx.x] + sh[3][threadIdx.x];
  }
}

// ---------- kernel2 (R6 verbatim) ----------
__global__ __launch_bounds__(256) void cos_final_kernel(
    const float* __restrict__ ws, const int* __restrict__ lens,
    float* __restrict__ out, int B) {
  const int wave = threadIdx.x >> 6;
  const int lane = threadIdx.x & 63;

  __shared__ float shl[BDIM];

  #pragma unroll
  for (int bi = 0; bi < 4; ++bi) {
    const int b = wave * 4 + bi;
    float v = 0.0f;
    #pragma unroll
    for (int m = 0; m < RBLKS / 64; ++m) v += ws[b * RBLKS + (m << 6) + lane];
    #pragma unroll
    for (int off = 1; off < 64; off <<= 1) v += __shfl_xor(v, off);
    if (lane == 0) {
      const int len = lens[b];
      shl[b] = (len > 0) ? (1.0f - v / (float)len) : 0.0f;
    }
  }
  __syncthreads();
  if (threadIdx.x == 0) {
    float t = 0.0f;
    #pragma unroll
    for (int i = 0; i < BDIM; ++i) t += shl[i];
    out[0] = t * (1.0f / BDIM);
  }
}

extern "C" void kernel_launch(void* const* d_in, const int* in_sizes, int n_in,
                              void* d_out, int out_size, void* d_ws, size_t ws_size,
                              hipStream_t stream) {
  const float* stat = (const float*)d_in[0];
  const float* con  = (const float*)d_in[1];
  const int*   lens = (const int*)d_in[2];
  float*       out  = (float*)d_out;
  float*       ws   = (float*)d_ws;              // floats [0, 4096): authoritative partials
  float*       ws2  = (float*)d_ws + WS2_OFF;    // floats [4096, 5120): probe scratch

  const int B = in_sizes[2];  // 16

  dim3 blk(256);
  // probe (timed A/B: total - 20.6us = probe's standalone duration)
  hipLaunchKernelGGL(cos_probe_kernel, dim3(1024), blk, 0, stream, stat, con, lens, ws2);
  // authoritative pipeline (unchanged R6)
  hipLaunchKernelGGL(cos_partial_kernel, dim3(NB1), blk, 0, stream, stat, con, lens, ws);
  hipLaunchKernelGGL(cos_final_kernel, dim3(1), blk, 0, stream, ws, lens, out, B);
}

// Round 12
// 18.613 us; speedup vs baseline: 2.2376x; 2.2376x over previous
//
#include <hip/hip_runtime.h>

#define NROWS 4096
#define DDIM  256
#define BDIM  16
#define RBLKS 256           // row-blocks, 16 rows each
#define BSETS 4             // 4 instances per block
#define NB1   (RBLKS * BSETS)  // 1024 blocks

typedef float v4f __attribute__((ext_vector_type(4)));

// Kernel 1: R6 structure (proven best), single change: NONTEMPORAL loads on
// the once-read 128MB stream (skip L2 allocation; pure streaming data).
// Wave: 4 groups of 16 lanes; group g owns row n; lane j covers cols
// {4j+64m : m=0..3} (256 B contiguous per group per load -> coalesced).
__global__ __launch_bounds__(256) void cos_partial_kernel(
    const float* __restrict__ stat, const float* __restrict__ con,
    const int* __restrict__ lens, float* __restrict__ ws) {
  const int rblk = blockIdx.x >> 2;
  const int bset = blockIdx.x & (BSETS - 1);
  const int wave = threadIdx.x >> 6;
  const int lane = threadIdx.x & 63;
  const int g    = lane >> 4;
  const int j    = lane & 15;

  const int n  = rblk * 16 + wave * 4 + g;
  const int b0 = bset * 4;

  float acc[4];
  #pragma unroll
  for (int bi = 0; bi < 4; ++bi) {
    const int b      = b0 + bi;
    const int len    = lens[b];
    const bool valid = (n < len);

    float dot = 0.0f, ns = 0.0f, nc = 0.0f;
    if (valid) {  // group-uniform; invalid rows cost no traffic
      const size_t base = (size_t)b * (NROWS * DDIM) + (size_t)n * DDIM + (j << 2);
      const v4f* pa = reinterpret_cast<const v4f*>(stat + base);
      const v4f* pc = reinterpret_cast<const v4f*>(con + base);
      #pragma unroll
      for (int m = 0; m < 4; ++m) {
        const v4f a = __builtin_nontemporal_load(pa + (m << 4)); // +64 floats
        const v4f c = __builtin_nontemporal_load(pc + (m << 4));
        dot = fmaf(a.x, c.x, fmaf(a.y, c.y, fmaf(a.z, c.z, fmaf(a.w, c.w, dot))));
        ns  = fmaf(a.x, a.x, fmaf(a.y, a.y, fmaf(a.z, a.z, fmaf(a.w, a.w, ns))));
        nc  = fmaf(c.x, c.x, fmaf(c.y, c.y, fmaf(c.z, c.z, fmaf(c.w, c.w, nc))));
      }
    }
    #pragma unroll
    for (int off = 1; off < 16; off <<= 1) {   // 4-stage, within 16-lane group
      dot += __shfl_xor(dot, off);
      ns  += __shfl_xor(ns,  off);
      nc  += __shfl_xor(nc,  off);
    }
    float cosv = valid ? dot * rsqrtf(ns) * rsqrtf(nc) : 0.0f; // eps unreachable
    cosv += __shfl_xor(cosv, 16);   // sum the wave's 4 row-groups
    cosv += __shfl_xor(cosv, 32);
    acc[bi] = cosv;
  }

  __shared__ float sh[4][4];
  if (lane == 0) {
    #pragma unroll
    for (int bi = 0; bi < 4; ++bi) sh[wave][bi] = acc[bi];
  }
  __syncthreads();
  if (threadIdx.x < 4) {
    const int b = b0 + threadIdx.x;
    ws[b * RBLKS + rblk] =
        sh[0][threadIdx.x] + sh[1][threadIdx.x] + sh[2][threadIdx.x] + sh[3][threadIdx.x];
  }
}

// Kernel 2: one block, 256 threads. Wave w reduces instances 4w..4w+3.
// NEW: float4 reads — one coalesced 1KB load covers an instance's 256 partials
// (4 load rounds instead of 16).
__global__ __launch_bounds__(256) void cos_final_kernel(
    const float* __restrict__ ws, const int* __restrict__ lens,
    float* __restrict__ out, int B) {
  const int wave = threadIdx.x >> 6;
  const int lane = threadIdx.x & 63;

  __shared__ float shl[BDIM];

  #pragma unroll
  for (int bi = 0; bi < 4; ++bi) {
    const int b = wave * 4 + bi;
    const v4f p = *reinterpret_cast<const v4f*>(ws + b * RBLKS + (lane << 2));
    float v = (p.x + p.y) + (p.z + p.w);
    #pragma unroll
    for (int off = 1; off < 64; off <<= 1) v += __shfl_xor(v, off);
    if (lane == 0) {
      const int len = lens[b];
      shl[b] = (len > 0) ? (1.0f - v / (float)len) : 0.0f;
    }
  }
  __syncthreads();
  if (threadIdx.x == 0) {
    float t = 0.0f;
    #pragma unroll
    for (int i = 0; i < BDIM; ++i) t += shl[i];
    out[0] = t * (1.0f / BDIM);
  }
}

extern "C" void kernel_launch(void* const* d_in, const int* in_sizes, int n_in,
                              void* d_out, int out_size, void* d_ws, size_t ws_size,
                              hipStream_t stream) {
  const float* stat = (const float*)d_in[0];
  const float* con  = (const float*)d_in[1];
  const int*   lens = (const int*)d_in[2];
  float*       out  = (float*)d_out;
  float*       ws   = (float*)d_ws;

  const int B = in_sizes[2];           // 16

  dim3 grid1(NB1);
  dim3 blk(256);
  hipLaunchKernelGGL(cos_partial_kernel, grid1, blk, 0, stream, stat, con, lens, ws);

  dim3 grid2(1);
  hipLaunchKernelGGL(cos_final_kernel, grid2, blk, 0, stream, ws, lens, out, B);
}

// Round 13
// 18.495 us; speedup vs baseline: 2.2519x; 1.0064x over previous
//
#include <hip/hip_runtime.h>

#define NROWS 4096
#define DDIM  256
#define BDIM  16
#define RBLKS 256           // row-blocks, 16 rows each
#define BSETS 8             // instance-pairs; 2 instances per block
#define NB1   (RBLKS * BSETS)  // 2048 blocks -> 8 blocks/CU, 32 waves/CU

typedef float v4f __attribute__((ext_vector_type(4)));

// Kernel 1 = R9's balanced mapping + R12's nontemporal loads.
// Block i: rblk = i>>3, bset = ((i&7) + (i>>8)) & 7. CU-resident blocks
// {c+256k} cover all 8 bsets at stratified rblk -> balanced per-CU work.
// 2048 blocks = 32 waves/CU: 2x the outstanding nt loads of R12 (nt bypasses
// L2 -> longer latency -> needs more TLP to saturate the read path).
// Wave: 4 groups of 16 lanes; group g owns row n; lane j covers cols
// {4j+64m : m=0..3} (256 B contiguous per group per load -> coalesced).
__global__ __launch_bounds__(256) void cos_partial_kernel(
    const float* __restrict__ stat, const float* __restrict__ con,
    const int* __restrict__ lens, float* __restrict__ ws) {
  const int i    = blockIdx.x;
  const int rblk = i >> 3;                     // 0..255
  const int bset = ((i & 7) + (i >> 8)) & 7;   // 0..7
  const int wave = threadIdx.x >> 6;
  const int lane = threadIdx.x & 63;
  const int g    = lane >> 4;
  const int j    = lane & 15;

  const int n  = rblk * 16 + wave * 4 + g;     // this lane's row
  const int b0 = bset * 2;

  float acc[2];
  #pragma unroll
  for (int bi = 0; bi < 2; ++bi) {
    const int b      = b0 + bi;
    const int len    = lens[b];
    const bool valid = (n < len);

    float dot = 0.0f, ns = 0.0f, nc = 0.0f;
    if (valid) {  // group-uniform; invalid rows cost no traffic
      const size_t base = (size_t)b * (NROWS * DDIM) + (size_t)n * DDIM + (j << 2);
      const v4f* pa = reinterpret_cast<const v4f*>(stat + base);
      const v4f* pc = reinterpret_cast<const v4f*>(con + base);
      #pragma unroll
      for (int m = 0; m < 4; ++m) {
        const v4f a = __builtin_nontemporal_load(pa + (m << 4)); // +64 floats
        const v4f c = __builtin_nontemporal_load(pc + (m << 4));
        dot = fmaf(a.x, c.x, fmaf(a.y, c.y, fmaf(a.z, c.z, fmaf(a.w, c.w, dot))));
        ns  = fmaf(a.x, a.x, fmaf(a.y, a.y, fmaf(a.z, a.z, fmaf(a.w, a.w, ns))));
        nc  = fmaf(c.x, c.x, fmaf(c.y, c.y, fmaf(c.z, c.z, fmaf(c.w, c.w, nc))));
      }
    }
    #pragma unroll
    for (int off = 1; off < 16; off <<= 1) {   // 4-stage, within 16-lane group
      dot += __shfl_xor(dot, off);
      ns  += __shfl_xor(ns,  off);
      nc  += __shfl_xor(nc,  off);
    }
    float cosv = valid ? dot * rsqrtf(ns) * rsqrtf(nc) : 0.0f; // eps unreachable
    cosv += __shfl_xor(cosv, 16);   // sum the wave's 4 row-groups
    cosv += __shfl_xor(cosv, 32);
    acc[bi] = cosv;
  }

  __shared__ float sh[4][2];
  if (lane == 0) {
    #pragma unroll
    for (int bi = 0; bi < 2; ++bi) sh[wave][bi] = acc[bi];
  }
  __syncthreads();
  if (threadIdx.x < 2) {
    const int b = b0 + threadIdx.x;
    ws[b * RBLKS + rblk] =
        sh[0][threadIdx.x] + sh[1][threadIdx.x] + sh[2][threadIdx.x] + sh[3][threadIdx.x];
  }
}

// Kernel 2: one block, 256 threads. Wave w reduces instances 4w..4w+3 via
// float4 reads (one coalesced 1KB load per instance), thread 0 combines.
__global__ __launch_bounds__(256) void cos_final_kernel(
    const float* __restrict__ ws, const int* __restrict__ lens,
    float* __restrict__ out, int B) {
  const int wave = threadIdx.x >> 6;
  const int lane = threadIdx.x & 63;

  __shared__ float shl[BDIM];

  #pragma unroll
  for (int bi = 0; bi < 4; ++bi) {
    const int b = wave * 4 + bi;
    const v4f p = *reinterpret_cast<const v4f*>(ws + b * RBLKS + (lane << 2));
    float v = (p.x + p.y) + (p.z + p.w);
    #pragma unroll
    for (int off = 1; off < 64; off <<= 1) v += __shfl_xor(v, off);
    if (lane == 0) {
      const int len = lens[b];
      shl[b] = (len > 0) ? (1.0f - v / (float)len) : 0.0f;
    }
  }
  __syncthreads();
  if (threadIdx.x == 0) {
    float t = 0.0f;
    #pragma unroll
    for (int i = 0; i < BDIM; ++i) t += shl[i];
    out[0] = t * (1.0f / BDIM);
  }
}

extern "C" void kernel_launch(void* const* d_in, const int* in_sizes, int n_in,
                              void* d_out, int out_size, void* d_ws, size_t ws_size,
                              hipStream_t stream) {
  const float* stat = (const float*)d_in[0];
  const float* con  = (const float*)d_in[1];
  const int*   lens = (const int*)d_in[2];
  float*       out  = (float*)d_out;
  float*       ws   = (float*)d_ws;

  const int B = in_sizes[2];           // 16

  dim3 grid1(NB1);
  dim3 blk(256);
  hipLaunchKernelGGL(cos_partial_kernel, grid1, blk, 0, stream, stat, con, lens, ws);

  dim3 grid2(1);
  hipLaunchKernelGGL(cos_final_kernel, grid2, blk, 0, stream, ws, lens, out, B);
}